// Round 2
// baseline (2448.978 us; speedup 1.0000x reference)
//
#include <hip/hip_runtime.h>

#define DMODEL 1024
#define DINNER 2048
#define DTRANK 64
#define NPROJ  96
#define BATCH  2
#define LIN    2048
#define LOUT   2049
#define MTOT0  4096   // BATCH*LIN
#define MTOT1  4098   // BATCH*LOUT
#define MP     4100   // padded column stride for (feature, B*L1) buffers
#define TC     64
#define NCH    33     // ceil(2049/64)

__device__ __forceinline__ float f_silu(float x)     { return x / (1.f + __expf(-x)); }
__device__ __forceinline__ float f_softplus(float x) { return (x > 20.f) ? x : log1pf(__expf(x)); }

// ===================== LayerNorm stats (mu, rstd per (b,l)) =====================
__global__ void ln_stats_k(const float* __restrict__ x, float* __restrict__ mu, float* __restrict__ rs)
{
    int b  = blockIdx.y;
    int l0 = blockIdx.x * 64;
    int lc = threadIdx.x & 63;
    int q  = threadIdx.x >> 6;          // 0..3
    const float* xb = x + (size_t)b * DMODEL * LIN + (l0 + lc);
    float s = 0.f, ss = 0.f;
    for (int c = q * 256; c < q * 256 + 256; ++c) {
        float v = xb[(size_t)c * LIN];
        s += v; ss += v * v;
    }
    __shared__ float Ss[4][64];
    __shared__ float Sq[4][64];
    Ss[q][lc] = s; Sq[q][lc] = ss;
    __syncthreads();
    if (threadIdx.x < 64) {
        float st = Ss[0][lc] + Ss[1][lc] + Ss[2][lc] + Ss[3][lc];
        float sq = Sq[0][lc] + Sq[1][lc] + Sq[2][lc] + Sq[3][lc];
        float m = st * (1.f / DMODEL);
        float v = sq * (1.f / DMODEL) - m * m;
        mu[b * LIN + l0 + lc] = m;
        rs[b * LIN + l0 + lc] = 1.f / sqrtf(v + 1e-5f);
    }
}

// ===================== GEMM: C[n][m] = sum_k A[k][m] * W[n][k] =====================
// A is (K x M) row-stride lda (feature-major activations).  W is (N x K) row-major.
// AMODE: 0 = plain A, 1 = LN-fused read from x (B,DMODEL,LIN layout)
// EPI:   0 = none, 1 = +bias, 2 = softplus(+bias), 3 = +bias & scatter to (B,DMODEL,LOUT)
#define BM 128
#define BN 128
#define BK 32

template<int AMODE, int EPI>
__global__ __launch_bounds__(256) void gemm_k(
    const float* __restrict__ A, int lda,
    const float* __restrict__ W, int ldb,
    float* __restrict__ C, int ldc,
    int M, int N, int K,
    const float* __restrict__ bias,
    const float* __restrict__ mu, const float* __restrict__ rs,
    const float* __restrict__ gam, const float* __restrict__ bet)
{
    __shared__ float As[BK][BM];
    __shared__ float Bs[BK][BN];
    int tid = threadIdx.x;
    int tx = tid & 15, ty = tid >> 4;
    int m0 = blockIdx.x * BM;
    int n0 = blockIdx.y * BN;

    float acc[8][8];
#pragma unroll
    for (int i = 0; i < 8; i++)
#pragma unroll
        for (int j = 0; j < 8; j++) acc[i][j] = 0.f;

    int ar = tid >> 3;       // 0..31 : k row staged by this thread
    int af = tid & 7;        // 0..7  : 16-col group
    int bRow  = tid >> 1;    // 0..127: n row staged
    int bHalf = tid & 1;     // 0..1  : 16-k group

    bool mfull = (m0 + BM <= M);

    for (int k0 = 0; k0 < K; k0 += BK) {
        // ---- stage A tile ----
        if (AMODE == 0) {
            const float* Ap = A + (size_t)(k0 + ar) * lda + m0 + af * 16;
            if (mfull) {
#pragma unroll
                for (int e4 = 0; e4 < 4; e4++) {
                    float4 v = *(const float4*)(Ap + e4 * 4);
                    *(float4*)&As[ar][af * 16 + e4 * 4] = v;
                }
            } else {
#pragma unroll
                for (int e = 0; e < 16; e++) {
                    int m = m0 + af * 16 + e;
                    As[ar][af * 16 + e] = (m < M) ? Ap[e] : 0.f;
                }
            }
        } else {
            // LN-fused from x: A[k=c][m=b*LIN+l]
            int c  = k0 + ar;
            int bq = m0 >> 11;            // tiles never straddle batches (LIN%BM==0)
            int l0 = (m0 & (LIN - 1)) + af * 16;
            const float* xp = A + (((size_t)bq * DMODEL + c) << 11) + l0;
            float g = gam[c], be = bet[c];
            const float* mup = mu + m0 + af * 16;
            const float* rsp = rs + m0 + af * 16;
#pragma unroll
            for (int e4 = 0; e4 < 4; e4++) {
                float4 xv = *(const float4*)(xp + e4 * 4);
                float4 m4 = *(const float4*)(mup + e4 * 4);
                float4 r4 = *(const float4*)(rsp + e4 * 4);
                As[ar][af * 16 + e4 * 4 + 0] = (xv.x - m4.x) * r4.x * g + be;
                As[ar][af * 16 + e4 * 4 + 1] = (xv.y - m4.y) * r4.y * g + be;
                As[ar][af * 16 + e4 * 4 + 2] = (xv.z - m4.z) * r4.z * g + be;
                As[ar][af * 16 + e4 * 4 + 3] = (xv.w - m4.w) * r4.w * g + be;
            }
        }
        // ---- stage B tile (transpose W rows into Bs[k][n]) ----
        {
            int n = n0 + bRow;
            if (n < N) {
                const float* Wp = W + (size_t)n * ldb + k0 + bHalf * 16;
#pragma unroll
                for (int e4 = 0; e4 < 4; e4++) {
                    float4 w = *(const float4*)(Wp + e4 * 4);
                    Bs[bHalf * 16 + e4 * 4 + 0][bRow] = w.x;
                    Bs[bHalf * 16 + e4 * 4 + 1][bRow] = w.y;
                    Bs[bHalf * 16 + e4 * 4 + 2][bRow] = w.z;
                    Bs[bHalf * 16 + e4 * 4 + 3][bRow] = w.w;
                }
            } else {
#pragma unroll
                for (int e = 0; e < 16; e++) Bs[bHalf * 16 + e][bRow] = 0.f;
            }
        }
        __syncthreads();

#pragma unroll
        for (int k = 0; k < BK; k++) {
            float4 a0 = *(const float4*)&As[k][tx * 4];
            float4 a1 = *(const float4*)&As[k][tx * 4 + 64];
            float4 b0 = *(const float4*)&Bs[k][ty * 4];
            float4 b1 = *(const float4*)&Bs[k][ty * 4 + 64];
            float am[8] = {a0.x, a0.y, a0.z, a0.w, a1.x, a1.y, a1.z, a1.w};
            float bv[8] = {b0.x, b0.y, b0.z, b0.w, b1.x, b1.y, b1.z, b1.w};
#pragma unroll
            for (int i = 0; i < 8; i++)
#pragma unroll
                for (int j = 0; j < 8; j++)
                    acc[i][j] += am[i] * bv[j];
        }
        __syncthreads();
    }

    // ---- epilogue ----
#pragma unroll
    for (int j = 0; j < 8; j++) {
        int n = n0 + ((j < 4) ? (ty * 4 + j) : (64 + ty * 4 + (j - 4)));
        if (n >= N) continue;
        float bv = (EPI >= 1) ? bias[n] : 0.f;
#pragma unroll
        for (int ih = 0; ih < 2; ih++) {
            int ml = (ih ? 64 : 0) + tx * 4;
            int m  = m0 + ml;
            float v[4];
#pragma unroll
            for (int e = 0; e < 4; e++) {
                float t = acc[ih * 4 + e][j] + bv;
                if (EPI == 2) t = f_softplus(t);
                v[e] = t;
            }
            if (EPI == 3) {
#pragma unroll
                for (int e = 0; e < 4; e++) {
                    int mm = m + e;
                    if (mm < M) {
                        int bq = (mm >= LOUT) ? 1 : 0;
                        int l  = mm - bq * LOUT;
                        C[((size_t)bq * DMODEL + n) * LOUT + l] = v[e];
                    }
                }
            } else {
                if (m + 3 < M) {
                    *(float4*)&C[(size_t)n * ldc + m] = make_float4(v[0], v[1], v[2], v[3]);
                } else {
#pragma unroll
                    for (int e = 0; e < 4; e++)
                        if (m + e < M) C[(size_t)n * ldc + m + e] = v[e];
                }
            }
        }
    }
}

// ===================== depthwise convs (along L, feature-major) =====================
__global__ void conv1_k(const float* __restrict__ h1, const float* __restrict__ cw,
                        const float* __restrict__ cb, float* __restrict__ h2)
{
    int j = blockIdx.y;
    int b = blockIdx.z;
    int l = blockIdx.x * 256 + threadIdx.x;
    if (l >= LOUT) return;
    const float* hp = h1 + (size_t)j * MTOT0 + b * LIN;
    float acc = cb[j];
    float w0 = cw[j * 4 + 0], w1 = cw[j * 4 + 1], w2 = cw[j * 4 + 2], w3 = cw[j * 4 + 3];
    int li;
    li = l - 2; if (li >= 0 && li < LIN) acc += hp[li] * w0;
    li = l - 1; if (li >= 0 && li < LIN) acc += hp[li] * w1;
    li = l;     if (li < LIN)            acc += hp[li] * w2;
    li = l + 1; if (li < LIN)            acc += hp[li] * w3;
    h2[(size_t)j * MP + b * LOUT + l] = f_silu(acc);
}

__global__ void conv2_k(const float* __restrict__ xi, const float* __restrict__ cw,
                        const float* __restrict__ cb, float* __restrict__ u)
{
    int d = blockIdx.y;
    int b = blockIdx.z;
    int l = blockIdx.x * 256 + threadIdx.x;
    if (l >= LOUT) return;
    const float* xp = xi + (size_t)d * MP + b * LOUT;
    float acc = cb[d];
#pragma unroll
    for (int k = 0; k < 4; k++) {
        int li = l - 3 + k;
        if (li >= 0) acc += xp[li] * cw[d * 4 + k];   // li <= l < LOUT
    }
    u[(size_t)d * MP + b * LOUT + l] = f_silu(acc);
}

// ===================== chunked selective scan =====================
// phase1: per (b,d,chunk): local state with h_in=0 and per-state decay product
__global__ void scan1_k(const float* __restrict__ dt, const float* __restrict__ u,
                        const float* __restrict__ xdbl, const float* __restrict__ A_log,
                        float* __restrict__ sP, float* __restrict__ sH)
{
    int d = blockIdx.x * 256 + threadIdx.x;
    int c = blockIdx.y;
    int b = blockIdx.z;
    int t0 = c * TC;
    int tlen = LOUT - t0; if (tlen > TC) tlen = TC;
    int mbase = b * LOUT + t0;

    float Ad[16], h[16], P[16];
#pragma unroll
    for (int s = 0; s < 16; s++) {
        Ad[s] = -__expf(A_log[d * 16 + s]);
        h[s] = 0.f; P[s] = 1.f;
    }
    const float* dtp = dt + (size_t)d * MP + mbase;
    const float* up  = u  + (size_t)d * MP + mbase;
    const float* Bp  = xdbl + (size_t)DTRANK * MP + mbase;
    for (int t = 0; t < tlen; t++) {
        float dtt = dtp[t];
        float du  = dtt * up[t];
#pragma unroll
        for (int s = 0; s < 16; s++) {
            float a  = __expf(dtt * Ad[s]);
            float Bv = Bp[(size_t)s * MP + t];
            h[s] = a * h[s] + du * Bv;
            P[s] *= a;
        }
    }
    size_t base = (((size_t)b * DINNER + d) * NCH + c) * 16;
#pragma unroll
    for (int s = 0; s < 16; s++) { sP[base + s] = P[s]; sH[base + s] = h[s]; }
}

// phase2: sequential combine across chunks; rewrite sH with incoming state per chunk
__global__ void scan2_k(const float* __restrict__ sP, float* __restrict__ sH)
{
    int t = blockIdx.x * 256 + threadIdx.x;    // B*DINNER*16 = 65536
    int s = t & 15;
    int d = (t >> 4) & (DINNER - 1);
    int b = t >> 15;
    size_t base = (((size_t)b * DINNER + d) * NCH) * 16 + s;
    float hrun = 0.f;
    for (int c = 0; c < NCH; c++) {
        size_t idx = base + (size_t)c * 16;
        float Pv = sP[idx], hl = sH[idx];
        sH[idx] = hrun;
        hrun = Pv * hrun + hl;
    }
}

// phase3: recompute with correct h_in, emit ym = (y + u*Dp) * silu(z)
__global__ void scan3_k(const float* __restrict__ dt, const float* __restrict__ u,
                        const float* __restrict__ xdbl, const float* __restrict__ A_log,
                        const float* __restrict__ Dp, const float* __restrict__ xzfull,
                        const float* __restrict__ sH, float* __restrict__ ym)
{
    int d = blockIdx.x * 256 + threadIdx.x;
    int c = blockIdx.y;
    int b = blockIdx.z;
    int t0 = c * TC;
    int tlen = LOUT - t0; if (tlen > TC) tlen = TC;
    int mbase = b * LOUT + t0;

    size_t base = (((size_t)b * DINNER + d) * NCH + c) * 16;
    float Ad[16], h[16];
#pragma unroll
    for (int s = 0; s < 16; s++) {
        Ad[s] = -__expf(A_log[d * 16 + s]);
        h[s] = sH[base + s];
    }
    float Dpd = Dp[d];
    const float* dtp = dt + (size_t)d * MP + mbase;
    const float* up  = u  + (size_t)d * MP + mbase;
    const float* Bp  = xdbl + (size_t)DTRANK * MP + mbase;
    const float* Cp  = xdbl + (size_t)(DTRANK + 16) * MP + mbase;
    const float* zp  = xzfull + (size_t)(DINNER + d) * MP + mbase;
    float* yp = ym + (size_t)d * MP + mbase;
    for (int t = 0; t < tlen; t++) {
        float dtt = dtp[t];
        float ut  = up[t];
        float du  = dtt * ut;
        float y = 0.f;
#pragma unroll
        for (int s = 0; s < 16; s++) {
            float a = __expf(dtt * Ad[s]);
            h[s] = a * h[s] + du * Bp[(size_t)s * MP + t];
            y += h[s] * Cp[(size_t)s * MP + t];
        }
        float z = zp[t];
        yp[t] = (y + ut * Dpd) * f_silu(z);
    }
}

// ===================== launcher =====================
extern "C" void kernel_launch(void* const* d_in, const int* in_sizes, int n_in,
                              void* d_out, int out_size, void* d_ws, size_t ws_size,
                              hipStream_t stream)
{
    (void)in_sizes; (void)n_in; (void)out_size; (void)ws_size;
    const float* x        = (const float*)d_in[0];
    const float* ln_g     = (const float*)d_in[1];
    const float* ln_b     = (const float*)d_in[2];
    const float* W_in     = (const float*)d_in[3];
    const float* b_in     = (const float*)d_in[4];
    const float* conv_w   = (const float*)d_in[5];
    const float* conv_b   = (const float*)d_in[6];
    const float* W_inproj = (const float*)d_in[7];
    const float* m_conv_w = (const float*)d_in[8];
    const float* m_conv_b = (const float*)d_in[9];
    const float* W_xproj  = (const float*)d_in[10];
    const float* W_dt     = (const float*)d_in[11];
    const float* b_dt     = (const float*)d_in[12];
    const float* A_log    = (const float*)d_in[13];
    const float* Dp       = (const float*)d_in[14];
    const float* W_outproj= (const float*)d_in[15];
    const float* W_out    = (const float*)d_in[16];
    const float* b_out    = (const float*)d_in[17];
    float* out = (float*)d_out;

    float* ws  = (float*)d_ws;
    float* mu   = ws;                                   // 4096
    float* rs   = ws + 4096;                            // 4096
    float* h1   = ws + 8192;                            // 1024*4096
    float* h2   = h1 + (size_t)DMODEL * MTOT0;          // 1024*4100
    float* xz   = h2 + (size_t)DMODEL * MP;             // 4096*4100
    float* uu   = xz + (size_t)(2 * DINNER) * MP;       // 2048*4100
    float* xdbl = uu + (size_t)DINNER * MP;             // 96*4100
    float* dt   = xdbl + (size_t)NPROJ * MP;            // 2048*4100
    float* sP   = dt + (size_t)DINNER * MP;             // 2*2048*33*16
    float* sH   = sP + (size_t)BATCH * DINNER * NCH * 16;
    float* ym   = xz;   // alias xi region (dead after conv2); z rows untouched
    float* o1   = uu;   // alias u (dead after scan3)

    // 1) LN stats
    ln_stats_k<<<dim3(32, 2), 256, 0, stream>>>(x, mu, rs);
    // 2) h1 = LN(x)^T @ W_in^T + b_in           (1024 x 4096)
    gemm_k<1, 1><<<dim3(32, 8), 256, 0, stream>>>(x, 0, W_in, DMODEL, h1, MTOT0,
        MTOT0, DMODEL, DMODEL, b_in, mu, rs, ln_g, ln_b);
    // 3) h2 = silu(dwconv(h1, pad(2,2)))        (1024 x 4098, stride MP)
    conv1_k<<<dim3(9, DMODEL, BATCH), 256, 0, stream>>>(h1, conv_w, conv_b, h2);
    // 4) xz = h2 @ W_inproj^T                   (4096 x 4098)
    gemm_k<0, 0><<<dim3(33, 32), 256, 0, stream>>>(h2, MP, W_inproj, DMODEL, xz, MP,
        MTOT1, 2 * DINNER, DMODEL, nullptr, nullptr, nullptr, nullptr, nullptr);
    // 5) u = silu(causal dwconv(xi))            (2048 x 4098)
    conv2_k<<<dim3(9, DINNER, BATCH), 256, 0, stream>>>(xz, m_conv_w, m_conv_b, uu);
    // 6) x_dbl = u @ W_xproj^T                  (96 x 4098)
    gemm_k<0, 0><<<dim3(33, 1), 256, 0, stream>>>(uu, MP, W_xproj, DINNER, xdbl, MP,
        MTOT1, NPROJ, DINNER, nullptr, nullptr, nullptr, nullptr, nullptr);
    // 7) dt = softplus(dtraw @ W_dt^T + b_dt)   (2048 x 4098)
    gemm_k<0, 2><<<dim3(33, 16), 256, 0, stream>>>(xdbl, MP, W_dt, DTRANK, dt, MP,
        MTOT1, DINNER, DTRANK, b_dt, nullptr, nullptr, nullptr, nullptr);
    // 8-10) chunked scan -> ym = (y + u*Dp)*silu(z)
    scan1_k<<<dim3(8, NCH, 2), 256, 0, stream>>>(dt, uu, xdbl, A_log, sP, sH);
    scan2_k<<<dim3(256), 256, 0, stream>>>(sP, sH);
    scan3_k<<<dim3(8, NCH, 2), 256, 0, stream>>>(dt, uu, xdbl, A_log, Dp, xz, sH, ym);
    // 11) o1 = ym @ W_outproj^T                 (1024 x 4098)
    gemm_k<0, 0><<<dim3(33, 8), 256, 0, stream>>>(ym, MP, W_outproj, DINNER, o1, MP,
        MTOT1, DMODEL, DINNER, nullptr, nullptr, nullptr, nullptr, nullptr);
    // 12) out = o1 @ W_out^T + b_out, scatter to (B, DMODEL, LOUT)
    gemm_k<0, 3><<<dim3(33, 8), 256, 0, stream>>>(o1, MP, W_out, DMODEL, out, 0,
        MTOT1, DMODEL, DMODEL, b_out, nullptr, nullptr, nullptr, nullptr);
}

// Round 5
// 675.130 us; speedup vs baseline: 3.6274x; 3.6274x over previous
//
#include <hip/hip_runtime.h>
#include <hip/hip_bf16.h>

#define DMODEL 1024
#define DINNER 2048
#define DTRANK 64
#define NPROJ  96
#define BATCH  2
#define LIN    2048
#define LOUT   2049
#define MTOT0  4096   // BATCH*LIN
#define MTOT1  4098   // BATCH*LOUT
#define TC     64
#define NCH    33     // ceil(2049/64)

typedef __attribute__((ext_vector_type(8))) short short8;
typedef __attribute__((ext_vector_type(4))) float f32x4;

__device__ __forceinline__ float f_silu(float x)     { return x / (1.f + __expf(-x)); }
__device__ __forceinline__ float f_softplus(float x) { return (x > 20.f) ? x : log1pf(__expf(x)); }
__device__ __forceinline__ short f2b(float x)
{
    __hip_bfloat16 b = __float2bfloat16(x);
    return *reinterpret_cast<short*>(&b);
}

// ===================== LayerNorm stats (mu, rstd per (b,l)) =====================
__global__ void ln_stats_k(const float* __restrict__ x, float* __restrict__ mu, float* __restrict__ rs)
{
    int b  = blockIdx.y;
    int l0 = blockIdx.x * 64;
    int lc = threadIdx.x & 63;
    int q  = threadIdx.x >> 6;          // 0..3
    const float* xb = x + (size_t)b * DMODEL * LIN + (l0 + lc);
    float s = 0.f, ss = 0.f;
    for (int c = q * 256; c < q * 256 + 256; ++c) {
        float v = xb[(size_t)c * LIN];
        s += v; ss += v * v;
    }
    __shared__ float Ss[4][64];
    __shared__ float Sq[4][64];
    Ss[q][lc] = s; Sq[q][lc] = ss;
    __syncthreads();
    if (threadIdx.x < 64) {
        float st = Ss[0][lc] + Ss[1][lc] + Ss[2][lc] + Ss[3][lc];
        float sq = Sq[0][lc] + Sq[1][lc] + Sq[2][lc] + Sq[3][lc];
        float m = st * (1.f / DMODEL);
        float v = sq * (1.f / DMODEL) - m * m;
        mu[b * LIN + l0 + lc] = m;
        rs[b * LIN + l0 + lc] = 1.f / sqrtf(v + 1e-5f);
    }
}

// ============ LN apply + transpose: x (B,DMODEL,LIN) -> h0T bf16 [m][c] ============
__global__ void lnT_k(const float* __restrict__ x, const float* __restrict__ mu,
                      const float* __restrict__ rs, const float* __restrict__ g,
                      const float* __restrict__ be, short* __restrict__ h0T)
{
    __shared__ float T[32][33];
    int l0 = blockIdx.x * 32;
    int c0 = blockIdx.y * 32;
    int b  = blockIdx.z;
    int tx = threadIdx.x & 31, ty = threadIdx.x >> 5;  // ty 0..7
    const float* xb = x + ((size_t)b * DMODEL + c0) * LIN + l0;
#pragma unroll
    for (int i = 0; i < 4; i++) {
        int cl = ty + 8 * i;
        T[cl][tx] = xb[(size_t)cl * LIN + tx];
    }
    __syncthreads();
    int c = c0 + tx;
    float gg = g[c], bb = be[c];
#pragma unroll
    for (int i = 0; i < 4; i++) {
        int ll = ty + 8 * i;
        int m = b * LIN + l0 + ll;
        float v = (T[tx][ll] - mu[m]) * rs[m] * gg + bb;
        h0T[(size_t)m * DMODEL + c] = f2b(v);
    }
}

// ===================== fp32 -> bf16 weight conversion =====================
__global__ void cvt_k(const float* __restrict__ src, short* __restrict__ dst, int n)
{
    int i = (blockIdx.x * 256 + threadIdx.x) * 4;
    if (i + 3 < n) {
        float4 v = *(const float4*)(src + i);
        dst[i + 0] = f2b(v.x); dst[i + 1] = f2b(v.y);
        dst[i + 2] = f2b(v.z); dst[i + 3] = f2b(v.w);
    } else {
        for (int e = 0; e < 4 && i + e < n; e++) dst[i + e] = f2b(src[i + e]);
    }
}

// ===================== bf16 MFMA GEMM: C[m][n] = sum_k A[m][k] * W[n][k] =====================
// A bf16 (M x K) row-stride lda, W bf16 (N x K) row-stride ldb, fp32 accumulate.
// EPI: 0 plain fp32 C | 1 +bias fp32 | 2 softplus(+bias) fp32 | 3 fp32 + bf16 copy (n<64) into Cb
//      4 bf16-only into Cb | 5 swapped-scatter: m=out-channel, n=position, +bias, write (B,DMODEL,LOUT)
template<int EPI>
__global__ __launch_bounds__(256) void gemm_bf(
    const short* __restrict__ A, int lda,
    const short* __restrict__ W, int ldb,
    float* __restrict__ C, int ldc,
    short* __restrict__ Cb, int ldcb,
    int M, int N, int K,
    const float* __restrict__ bias)
{
    __shared__ short As[128][40];
    __shared__ short Bs[128][40];
    int tid  = threadIdx.x;
    int lane = tid & 63, wid = tid >> 6;
    int wr = wid >> 1, wc = wid & 1;          // wave quadrant (2x2 of 64x64)
    int fr = lane & 15, kg = lane >> 4;       // fragment row/col + k-group
    int m0 = blockIdx.x * 128, n0 = blockIdx.y * 128;
    int sr = tid >> 1, sh = (tid & 1) * 16;   // staging: row, 16-elem half

    f32x4 acc[4][4];
#pragma unroll
    for (int mi = 0; mi < 4; mi++)
#pragma unroll
        for (int ni = 0; ni < 4; ni++) acc[mi][ni] = (f32x4){0.f, 0.f, 0.f, 0.f};

    const short8 zz = {0, 0, 0, 0, 0, 0, 0, 0};

    for (int k0 = 0; k0 < K; k0 += 32) {
        short8 a0 = zz, a1 = zz, b0 = zz, b1 = zz;
        if (m0 + sr < M) {
            const short* p = A + (size_t)(m0 + sr) * lda + k0 + sh;
            a0 = *(const short8*)p;
            a1 = *(const short8*)(p + 8);
        }
        if (n0 + sr < N) {
            const short* p = W + (size_t)(n0 + sr) * ldb + k0 + sh;
            b0 = *(const short8*)p;
            b1 = *(const short8*)(p + 8);
        }
        *(short8*)&As[sr][sh]     = a0;
        *(short8*)&As[sr][sh + 8] = a1;
        *(short8*)&Bs[sr][sh]     = b0;
        *(short8*)&Bs[sr][sh + 8] = b1;
        __syncthreads();

        short8 af[4], bfr[4];
#pragma unroll
        for (int mi = 0; mi < 4; mi++)
            af[mi] = *(const short8*)&As[wr * 64 + mi * 16 + fr][kg * 8];
#pragma unroll
        for (int ni = 0; ni < 4; ni++)
            bfr[ni] = *(const short8*)&Bs[wc * 64 + ni * 16 + fr][kg * 8];
#pragma unroll
        for (int mi = 0; mi < 4; mi++)
#pragma unroll
            for (int ni = 0; ni < 4; ni++)
                acc[mi][ni] = __builtin_amdgcn_mfma_f32_16x16x32_bf16(
                    af[mi], bfr[ni], acc[mi][ni], 0, 0, 0);
        __syncthreads();
    }

    // epilogue: D element (m_local, n_local): n_local = lane&15, m_local = (lane>>4)*4 + reg
#pragma unroll
    for (int ni = 0; ni < 4; ni++) {
        int n = n0 + wc * 64 + ni * 16 + fr;
        if (n >= N) continue;
        float bv = 0.f;
        if (EPI == 1 || EPI == 2) bv = bias[n];
#pragma unroll
        for (int mi = 0; mi < 4; mi++) {
#pragma unroll
            for (int r = 0; r < 4; r++) {
                int m = m0 + wr * 64 + mi * 16 + kg * 4 + r;
                if (m >= M) continue;
                float v = acc[mi][ni][r];
                if (EPI == 1) v += bv;
                if (EPI == 2) v = f_softplus(v + bv);
                if (EPI == 5) {
                    float vb = v + bias[m];
                    int bq = (n >= LOUT) ? 1 : 0;
                    int l  = n - bq * LOUT;
                    C[((size_t)bq * DMODEL + m) * LOUT + l] = vb;
                } else if (EPI == 4) {
                    Cb[(size_t)m * ldcb + n] = f2b(v);
                } else {
                    C[(size_t)m * ldc + n] = v;
                    if (EPI == 3 && n < DTRANK) Cb[(size_t)m * ldcb + n] = f2b(v);
                }
            }
        }
    }
}

// ===================== depthwise convs (position-major, lanes = feature) =====================
__global__ void conv1_k(const float* __restrict__ h1, const float* __restrict__ cw,
                        const float* __restrict__ cb, short* __restrict__ h2b)
{
    int c = blockIdx.x * 256 + threadIdx.x;     // 0..1023
    int m = blockIdx.y;                         // 0..4097
    int b = (m >= LOUT) ? 1 : 0;
    int l = m - b * LOUT;
    float4 wv = ((const float4*)cw)[c];
    const float* w = (const float*)&wv;
    float acc = cb[c];
#pragma unroll
    for (int k = 0; k < 4; k++) {
        int li = l - 2 + k;
        if (li >= 0 && li < LIN)
            acc += h1[((size_t)b * LIN + li) * DMODEL + c] * w[k];
    }
    h2b[(size_t)m * DMODEL + c] = f2b(f_silu(acc));
}

__global__ void conv2_k(const float* __restrict__ xz, const float* __restrict__ cw,
                        const float* __restrict__ cb, float* __restrict__ u,
                        short* __restrict__ ub)
{
    int d = blockIdx.x * 256 + threadIdx.x;     // 0..2047
    int m = blockIdx.y;
    int b = (m >= LOUT) ? 1 : 0;
    int l = m - b * LOUT;
    float4 wv = ((const float4*)cw)[d];
    const float* w = (const float*)&wv;
    float acc = cb[d];
#pragma unroll
    for (int k = 0; k < 4; k++) {
        int li = l - 3 + k;                     // causal pad(3,0)
        if (li >= 0)
            acc += xz[((size_t)b * LOUT + li) * (2 * DINNER) + d] * w[k];
    }
    float s = f_silu(acc);
    u [(size_t)m * DINNER + d] = s;
    ub[(size_t)m * DINNER + d] = f2b(s);
}

// ===================== chunked selective scan (position-major) =====================
__global__ void scan1_k(const float* __restrict__ dt, const float* __restrict__ u,
                        const float* __restrict__ xdbl, const float* __restrict__ A_log,
                        float* __restrict__ sP, float* __restrict__ sH)
{
    int d = blockIdx.x * 256 + threadIdx.x;
    int c = blockIdx.y;
    int b = blockIdx.z;
    int t0 = c * TC;
    int tlen = LOUT - t0; if (tlen > TC) tlen = TC;

    float Ad[16], h[16], P[16];
#pragma unroll
    for (int q = 0; q < 4; q++) {
        float4 av = ((const float4*)A_log)[d * 4 + q];
        Ad[q*4+0] = -__expf(av.x); Ad[q*4+1] = -__expf(av.y);
        Ad[q*4+2] = -__expf(av.z); Ad[q*4+3] = -__expf(av.w);
    }
#pragma unroll
    for (int s = 0; s < 16; s++) { h[s] = 0.f; P[s] = 1.f; }

    size_t row0 = (size_t)b * LOUT + t0;
    const float* dtp = dt + row0 * DINNER + d;
    const float* up  = u  + row0 * DINNER + d;
    const float* Bp  = xdbl + row0 * NPROJ + DTRANK;
    for (int t = 0; t < tlen; t++) {
        float dtt = dtp[(size_t)t * DINNER];
        float du  = dtt * up[(size_t)t * DINNER];
        const float* Bt = Bp + (size_t)t * NPROJ;
#pragma unroll
        for (int s = 0; s < 16; s++) {
            float a = __expf(dtt * Ad[s]);
            h[s] = a * h[s] + du * Bt[s];
            P[s] *= a;
        }
    }
    size_t base = ((size_t)(b * NCH + c) * 16) * DINNER + d;
#pragma unroll
    for (int s = 0; s < 16; s++) {
        sP[base + (size_t)s * DINNER] = P[s];
        sH[base + (size_t)s * DINNER] = h[s];
    }
}

__global__ void scan2_k(const float* __restrict__ sP, float* __restrict__ sH)
{
    int gid = blockIdx.x * 256 + threadIdx.x;   // B*16*DINNER = 65536
    int d = gid & (DINNER - 1);
    int s = (gid >> 11) & 15;
    int b = gid >> 15;
    size_t base = ((size_t)(b * NCH) * 16 + s) * DINNER + d;
    const size_t cstep = (size_t)16 * DINNER;
    float hrun = 0.f;
    for (int c = 0; c < NCH; c++) {
        size_t idx = base + (size_t)c * cstep;
        float Pv = sP[idx], hl = sH[idx];
        sH[idx] = hrun;
        hrun = Pv * hrun + hl;
    }
}

__global__ void scan3_k(const float* __restrict__ dt, const float* __restrict__ u,
                        const float* __restrict__ xdbl, const float* __restrict__ A_log,
                        const float* __restrict__ Dp, const float* __restrict__ xz,
                        const float* __restrict__ sH, short* __restrict__ ymb)
{
    int d = blockIdx.x * 256 + threadIdx.x;
    int c = blockIdx.y;
    int b = blockIdx.z;
    int t0 = c * TC;
    int tlen = LOUT - t0; if (tlen > TC) tlen = TC;

    float Ad[16], h[16];
#pragma unroll
    for (int q = 0; q < 4; q++) {
        float4 av = ((const float4*)A_log)[d * 4 + q];
        Ad[q*4+0] = -__expf(av.x); Ad[q*4+1] = -__expf(av.y);
        Ad[q*4+2] = -__expf(av.z); Ad[q*4+3] = -__expf(av.w);
    }
    size_t sbase = ((size_t)(b * NCH + c) * 16) * DINNER + d;
#pragma unroll
    for (int s = 0; s < 16; s++) h[s] = sH[sbase + (size_t)s * DINNER];

    float Dpd = Dp[d];
    size_t row0 = (size_t)b * LOUT + t0;
    const float* dtp = dt + row0 * DINNER + d;
    const float* up  = u  + row0 * DINNER + d;
    const float* Bp  = xdbl + row0 * NPROJ + DTRANK;
    const float* Cp  = Bp + 16;
    const float* zp  = xz + row0 * (2 * DINNER) + DINNER + d;
    short* yp = ymb + row0 * DINNER + d;
    for (int t = 0; t < tlen; t++) {
        float dtt = dtp[(size_t)t * DINNER];
        float ut  = up[(size_t)t * DINNER];
        float du  = dtt * ut;
        const float* Bt = Bp + (size_t)t * NPROJ;
        const float* Ct = Cp + (size_t)t * NPROJ;
        float y = 0.f;
#pragma unroll
        for (int s = 0; s < 16; s++) {
            float a = __expf(dtt * Ad[s]);
            h[s] = a * h[s] + du * Bt[s];
            y += h[s] * Ct[s];
        }
        float z = zp[(size_t)t * (2 * DINNER)];
        yp[(size_t)t * DINNER] = f2b((y + ut * Dpd) * f_silu(z));
    }
}

// ===================== launcher =====================
extern "C" void kernel_launch(void* const* d_in, const int* in_sizes, int n_in,
                              void* d_out, int out_size, void* d_ws, size_t ws_size,
                              hipStream_t stream)
{
    (void)in_sizes; (void)n_in; (void)out_size; (void)ws_size;
    const float* x        = (const float*)d_in[0];
    const float* ln_g     = (const float*)d_in[1];
    const float* ln_b     = (const float*)d_in[2];
    const float* W_in     = (const float*)d_in[3];
    const float* b_in     = (const float*)d_in[4];
    const float* conv_w   = (const float*)d_in[5];
    const float* conv_b   = (const float*)d_in[6];
    const float* W_inproj = (const float*)d_in[7];
    const float* m_conv_w = (const float*)d_in[8];
    const float* m_conv_b = (const float*)d_in[9];
    const float* W_xproj  = (const float*)d_in[10];
    const float* W_dt     = (const float*)d_in[11];
    const float* b_dt     = (const float*)d_in[12];
    const float* A_log    = (const float*)d_in[13];
    const float* Dp       = (const float*)d_in[14];
    const float* W_outproj= (const float*)d_in[15];
    const float* W_out    = (const float*)d_in[16];
    const float* b_out    = (const float*)d_in[17];
    float* out = (float*)d_out;

    // ---- fp32 region ----
    float* F    = (float*)d_ws;
    float* mu   = F;                                    //      4096
    float* rs   = F + 4096;                             //      4096
    float* h1   = F + 8192;                             // 4096*1024 = 4,194,304
    float* xz   = h1 + (size_t)MTOT0 * DMODEL;          // 4098*4096 = 16,785,408
    float* uu   = xz + (size_t)MTOT1 * 2 * DINNER;      // 4098*2048 =  8,392,704
    float* xdbl = uu + (size_t)MTOT1 * DINNER;          // 4098*96   =    393,408
    float* dt   = xdbl + (size_t)MTOT1 * NPROJ;         // 4098*2048 =  8,392,704
    float* sP   = dt + (size_t)MTOT1 * DINNER;          // 2,162,688
    float* sH   = sP + (size_t)BATCH * NCH * 16 * DINNER;
    float* fend = sH + (size_t)BATCH * NCH * 16 * DINNER;

    // ---- bf16 region ----
    short* S     = (short*)fend;
    short* h0T   = S;                                   // 4096*1024
    short* h2b   = h0T + (size_t)MTOT0 * DMODEL;        // 4098*1024
    short* ub    = h2b + (size_t)MTOT1 * DMODEL;        // 4098*2048
    short* Wib   = ub  + (size_t)MTOT1 * DINNER;        // 1024*1024
    short* Winpb = Wib   + (size_t)DMODEL * DMODEL;     // 4096*1024
    short* Wxpb  = Winpb + (size_t)(2*DINNER) * DMODEL; // 96*2048
    short* Wdtb  = Wxpb  + (size_t)NPROJ * DINNER;      // 2048*64
    short* Wopb  = Wdtb  + (size_t)DINNER * DTRANK;     // 1024*2048
    short* Wob   = Wopb  + (size_t)DMODEL * DINNER;     // 1024*1024
    // aliases (lifetime-disjoint):
    short* dtin  = h0T;            // dtin [4098][64]; h0T dead after h1-GEMM
    short* ymb   = ub;             // ymb  [4098][2048]; ub dead after xproj-GEMM
    short* o1b   = (short*)h1;     // o1b  [4098][1024]; h1 dead after conv1

    // 0) weight conversions to bf16
    cvt_k<<<1024, 256, 0, stream>>>(W_in,      Wib,   DMODEL * DMODEL);
    cvt_k<<<4096, 256, 0, stream>>>(W_inproj,  Winpb, 2 * DINNER * DMODEL);
    cvt_k<<<192,  256, 0, stream>>>(W_xproj,   Wxpb,  NPROJ * DINNER);
    cvt_k<<<128,  256, 0, stream>>>(W_dt,      Wdtb,  DINNER * DTRANK);
    cvt_k<<<2048, 256, 0, stream>>>(W_outproj, Wopb,  DMODEL * DINNER);
    cvt_k<<<1024, 256, 0, stream>>>(W_out,     Wob,   DMODEL * DMODEL);
    // 1) LN stats + LN-apply/transpose -> h0T bf16 [m][c]
    ln_stats_k<<<dim3(32, 2), 256, 0, stream>>>(x, mu, rs);
    lnT_k<<<dim3(64, 32, 2), 256, 0, stream>>>(x, mu, rs, ln_g, ln_b, h0T);
    // 2) h1 = h0T @ W_in^T + b_in                  (4096 x 1024) fp32
    gemm_bf<1><<<dim3(32, 8), 256, 0, stream>>>(h0T, DMODEL, Wib, DMODEL,
        h1, DMODEL, nullptr, 0, MTOT0, DMODEL, DMODEL, b_in);
    // 3) h2b = bf16(silu(dwconv(h1, pad(2,2))))    (4098 x 1024)
    conv1_k<<<dim3(4, MTOT1), 256, 0, stream>>>(h1, conv_w, conv_b, h2b);
    // 4) xz = h2b @ W_inproj^T                     (4098 x 4096) fp32
    gemm_bf<0><<<dim3(33, 32), 256, 0, stream>>>(h2b, DMODEL, Winpb, DMODEL,
        xz, 2 * DINNER, nullptr, 0, MTOT1, 2 * DINNER, DMODEL, nullptr);
    // 5) u/ub = silu(causal dwconv(xi))            (4098 x 2048)
    conv2_k<<<dim3(8, MTOT1), 256, 0, stream>>>(xz, m_conv_w, m_conv_b, uu, ub);
    // 6) xdbl = ub @ W_xproj^T (+ bf16 dt-input copy)   (4098 x 96)
    gemm_bf<3><<<dim3(33, 1), 256, 0, stream>>>(ub, DINNER, Wxpb, DINNER,
        xdbl, NPROJ, dtin, DTRANK, MTOT1, NPROJ, DINNER, nullptr);
    // 7) dt = softplus(dtin @ W_dt^T + b_dt)       (4098 x 2048) fp32
    gemm_bf<2><<<dim3(33, 16), 256, 0, stream>>>(dtin, DTRANK, Wdtb, DTRANK,
        dt, DINNER, nullptr, 0, MTOT1, DINNER, DTRANK, b_dt);
    // 8-10) chunked scan -> ymb = bf16((y + u*Dp)*silu(z))
    scan1_k<<<dim3(8, NCH, 2), 256, 0, stream>>>(dt, uu, xdbl, A_log, sP, sH);
    scan2_k<<<dim3(256), 256, 0, stream>>>(sP, sH);
    scan3_k<<<dim3(8, NCH, 2), 256, 0, stream>>>(dt, uu, xdbl, A_log, Dp, xz, sH, ymb);
    // 11) o1b = bf16(ymb @ W_outproj^T)            (4098 x 1024)
    gemm_bf<4><<<dim3(33, 8), 256, 0, stream>>>(ymb, DINNER, Wopb, DINNER,
        nullptr, 0, o1b, DMODEL, MTOT1, DMODEL, DINNER, nullptr);
    // 12) out = o1b @ W_out^T + b_out, operand-swapped scatter to (B, DMODEL, LOUT)
    gemm_bf<5><<<dim3(8, 33), 256, 0, stream>>>(Wob, DMODEL, o1b, DMODEL,
        out, 0, nullptr, 0, DMODEL, MTOT1, DMODEL, b_out);
}

// Round 8
// 603.422 us; speedup vs baseline: 4.0585x; 1.1188x over previous
//
#include <hip/hip_runtime.h>
#include <hip/hip_bf16.h>

#define DMODEL 1024
#define DINNER 2048
#define DTRANK 64
#define NPROJ  96
#define BATCH  2
#define LIN    2048
#define LOUT   2049
#define MTOT0  4096   // BATCH*LIN
#define MTOT1  4098   // BATCH*LOUT
#define TC     64
#define NCH    33     // ceil(2049/64)

typedef __attribute__((ext_vector_type(8))) short short8;
typedef __attribute__((ext_vector_type(4))) float f32x4;

__device__ __forceinline__ float f_silu(float x)     { return x / (1.f + __expf(-x)); }
__device__ __forceinline__ float f_softplus(float x) { return (x > 20.f) ? x : log1pf(__expf(x)); }
__device__ __forceinline__ short f2b(float x)
{
    __hip_bfloat16 b = __float2bfloat16(x);
    return *reinterpret_cast<short*>(&b);
}
__device__ __forceinline__ float b2f(short s)
{
    return __uint_as_float(((unsigned)(unsigned short)s) << 16);
}
// async global->LDS, 16B per lane; dst = wave-uniform base + lane*16
__device__ __forceinline__ void gload16(const void* g, void* l)
{
    __builtin_amdgcn_global_load_lds(
        (const __attribute__((address_space(1))) void*)g,
        (__attribute__((address_space(3))) void*)l,
        16, 0, 0);
}

// ===================== LayerNorm stats (mu, rstd per (b,l)) =====================
__global__ void ln_stats_k(const float* __restrict__ x, float* __restrict__ mu, float* __restrict__ rs)
{
    int b  = blockIdx.y;
    int l0 = blockIdx.x * 64;
    int lc = threadIdx.x & 63;
    int q  = threadIdx.x >> 6;          // 0..3
    const float* xb = x + (size_t)b * DMODEL * LIN + (l0 + lc);
    float s = 0.f, ss = 0.f;
    for (int c = q * 256; c < q * 256 + 256; ++c) {
        float v = xb[(size_t)c * LIN];
        s += v; ss += v * v;
    }
    __shared__ float Ss[4][64];
    __shared__ float Sq[4][64];
    Ss[q][lc] = s; Sq[q][lc] = ss;
    __syncthreads();
    if (threadIdx.x < 64) {
        float st = Ss[0][lc] + Ss[1][lc] + Ss[2][lc] + Ss[3][lc];
        float sq = Sq[0][lc] + Sq[1][lc] + Sq[2][lc] + Sq[3][lc];
        float m = st * (1.f / DMODEL);
        float v = sq * (1.f / DMODEL) - m * m;
        mu[b * LIN + l0 + lc] = m;
        rs[b * LIN + l0 + lc] = 1.f / sqrtf(v + 1e-5f);
    }
}

// ============ LN apply + transpose: x (B,DMODEL,LIN) -> h0T bf16 [m][c] ============
__global__ void lnT_k(const float* __restrict__ x, const float* __restrict__ mu,
                      const float* __restrict__ rs, const float* __restrict__ g,
                      const float* __restrict__ be, short* __restrict__ h0T)
{
    __shared__ float T[32][33];
    int l0 = blockIdx.x * 32;
    int c0 = blockIdx.y * 32;
    int b  = blockIdx.z;
    int tx = threadIdx.x & 31, ty = threadIdx.x >> 5;  // ty 0..7
    const float* xb = x + ((size_t)b * DMODEL + c0) * LIN + l0;
#pragma unroll
    for (int i = 0; i < 4; i++) {
        int cl = ty + 8 * i;
        T[cl][tx] = xb[(size_t)cl * LIN + tx];
    }
    __syncthreads();
    int c = c0 + tx;
    float gg = g[c], bb = be[c];
#pragma unroll
    for (int i = 0; i < 4; i++) {
        int ll = ty + 8 * i;
        int m = b * LIN + l0 + ll;
        float v = (T[tx][ll] - mu[m]) * rs[m] * gg + bb;
        h0T[(size_t)m * DMODEL + c] = f2b(v);
    }
}

// ===================== single fused fp32 -> bf16 weight conversion =====================
// block ranges (each block = 1024 elements): W_in 1024 | W_inproj 4096 | W_xproj 192 |
// W_dt 128 | W_outproj 2048 | W_out 1024   (total 8512)
__global__ void cvt_all_k(const float* __restrict__ W_in, const float* __restrict__ W_inproj,
                          const float* __restrict__ W_xproj, const float* __restrict__ W_dt,
                          const float* __restrict__ W_outproj, const float* __restrict__ W_out,
                          short* __restrict__ Wib, short* __restrict__ Winpb,
                          short* __restrict__ Wxpb, short* __restrict__ Wdtb,
                          short* __restrict__ Wopb, short* __restrict__ Wob)
{
    int b = blockIdx.x;
    const float* s; short* d; int i;
    if      (b < 1024) { s = W_in;      d = Wib;   i = b; }
    else if (b < 5120) { s = W_inproj;  d = Winpb; i = b - 1024; }
    else if (b < 5312) { s = W_xproj;   d = Wxpb;  i = b - 5120; }
    else if (b < 5440) { s = W_dt;      d = Wdtb;  i = b - 5312; }
    else if (b < 7488) { s = W_outproj; d = Wopb;  i = b - 5440; }
    else               { s = W_out;     d = Wob;   i = b - 7488; }
    int idx = (i * 256 + threadIdx.x) * 4;
    float4 v = *(const float4*)(s + idx);
    d[idx + 0] = f2b(v.x); d[idx + 1] = f2b(v.y);
    d[idx + 2] = f2b(v.z); d[idx + 3] = f2b(v.w);
}

// ===================== bf16 MFMA GEMM: C[m][n] = sum_k A[m][k] * W[n][k] =====================
// global_load_lds staging (width 16), linear LDS [128][32] bf16, no padding.
// NOTE: tail tiles issue unpredicated OOB-row reads; garbage only reaches garbage-(m|n)
// accumulator elements (MFMA has no cross-row mixing) and is masked at store. All
// overreads verified to land inside live workspace regions.
// EPI: 0 plain fp32 C | 1 +bias fp32 | 4 bf16-only into Cb | 5 swapped-scatter (+bias[m])
template<int EPI>
__global__ __launch_bounds__(256) void gemm_bf(
    const short* __restrict__ A, int lda,
    const short* __restrict__ W, int ldb,
    float* __restrict__ C, int ldc,
    short* __restrict__ Cb, int ldcb,
    int M, int N, int K,
    const float* __restrict__ bias)
{
    __shared__ short As[128 * 32];
    __shared__ short Bs[128 * 32];
    int tid  = threadIdx.x;
    int lane = tid & 63, wid = tid >> 6;
    int wr = wid >> 1, wc = wid & 1;          // wave quadrant (2x2 of 64x64)
    int fr = lane & 15, kg = lane >> 4;       // fragment row + k-group
    int m0 = blockIdx.x * 128, n0 = blockIdx.y * 128;

    // staging map: round r in {0,1}: row = (wid*2+r)*16 + lane/4, col = (lane&3)*8 elems
    int scol  = (lane & 3) * 8;
    int srow0 = wid * 32 + (lane >> 2);
    int srow1 = srow0 + 16;
    const short* a0 = A + (size_t)(m0 + srow0) * lda + scol;
    const short* a1 = A + (size_t)(m0 + srow1) * lda + scol;
    const short* b0 = W + (size_t)(n0 + srow0) * ldb + scol;
    const short* b1 = W + (size_t)(n0 + srow1) * ldb + scol;
    char* asd0 = (char*)As + (wid * 2 + 0) * 1024;
    char* asd1 = (char*)As + (wid * 2 + 1) * 1024;
    char* bsd0 = (char*)Bs + (wid * 2 + 0) * 1024;
    char* bsd1 = (char*)Bs + (wid * 2 + 1) * 1024;

    f32x4 acc[4][4];
#pragma unroll
    for (int mi = 0; mi < 4; mi++)
#pragma unroll
        for (int ni = 0; ni < 4; ni++) acc[mi][ni] = (f32x4){0.f, 0.f, 0.f, 0.f};

    for (int k0 = 0; k0 < K; k0 += 32) {
        gload16(a0 + k0, asd0);
        gload16(a1 + k0, asd1);
        gload16(b0 + k0, bsd0);
        gload16(b1 + k0, bsd1);
        __syncthreads();

        short8 af[4], bf[4];
#pragma unroll
        for (int mi = 0; mi < 4; mi++)
            af[mi] = *(const short8*)&As[(wr * 64 + mi * 16 + fr) * 32 + kg * 8];
#pragma unroll
        for (int ni = 0; ni < 4; ni++)
            bf[ni] = *(const short8*)&Bs[(wc * 64 + ni * 16 + fr) * 32 + kg * 8];
#pragma unroll
        for (int mi = 0; mi < 4; mi++)
#pragma unroll
            for (int ni = 0; ni < 4; ni++)
                acc[mi][ni] = __builtin_amdgcn_mfma_f32_16x16x32_bf16(
                    af[mi], bf[ni], acc[mi][ni], 0, 0, 0);
        __syncthreads();
    }

    // epilogue: D element (m_local, n_local): n_local = lane&15, m_local = (lane>>4)*4 + reg
#pragma unroll
    for (int ni = 0; ni < 4; ni++) {
        int n = n0 + wc * 64 + ni * 16 + fr;
        if (n >= N) continue;
        float bv = 0.f;
        if (EPI == 1) bv = bias[n];
#pragma unroll
        for (int mi = 0; mi < 4; mi++) {
#pragma unroll
            for (int r = 0; r < 4; r++) {
                int m = m0 + wr * 64 + mi * 16 + kg * 4 + r;
                if (m >= M) continue;
                float v = acc[mi][ni][r];
                if (EPI == 1) v += bv;
                if (EPI == 5) {
                    float vb = v + bias[m];
                    int bq = (n >= LOUT) ? 1 : 0;
                    int l  = n - bq * LOUT;
                    C[((size_t)bq * DMODEL + m) * LOUT + l] = vb;
                } else if (EPI == 4) {
                    Cb[(size_t)m * ldcb + n] = f2b(v);
                } else {
                    C[(size_t)m * ldc + n] = v;
                }
            }
        }
    }
}

// ============ fused dt kernel: dt[m][n] = softplus(xdbl[m][0:64] . W_dt[n] + b_dt[n]) ============
// block: 4 m-rows x N=2048; thread: 8 consecutive n
__global__ __launch_bounds__(256) void dtfuse_k(const float* __restrict__ xdbl,
                                                const short* __restrict__ Wdtb,
                                                const float* __restrict__ b_dt,
                                                float* __restrict__ dtout)
{
    int t  = threadIdx.x;
    int m0 = blockIdx.x * 4;
    __shared__ float dr[4][64];
    int mr = m0 + (t >> 6);
    dr[t >> 6][t & 63] = (mr < MTOT1) ? xdbl[(size_t)mr * NPROJ + (t & 63)] : 0.f;
    __syncthreads();

    int n = t * 8;
    float acc[4][8];
#pragma unroll
    for (int j = 0; j < 8; j++) {
        float bj = b_dt[n + j];
#pragma unroll
        for (int mi = 0; mi < 4; mi++) acc[mi][j] = bj;
    }
    for (int kk = 0; kk < 64; kk += 8) {
        float w[8][8];
#pragma unroll
        for (int j = 0; j < 8; j++) {
            short8 wv = *(const short8*)&Wdtb[(size_t)(n + j) * 64 + kk];
#pragma unroll
            for (int e = 0; e < 8; e++) w[j][e] = b2f(wv[e]);
        }
#pragma unroll
        for (int mi = 0; mi < 4; mi++) {
            float d[8];
#pragma unroll
            for (int e = 0; e < 8; e++) d[e] = dr[mi][kk + e];
#pragma unroll
            for (int j = 0; j < 8; j++)
#pragma unroll
                for (int e = 0; e < 8; e++) acc[mi][j] += d[e] * w[j][e];
        }
    }
#pragma unroll
    for (int mi = 0; mi < 4; mi++) {
        int m = m0 + mi;
        if (m >= MTOT1) continue;
        float4 o0, o1;
        o0.x = f_softplus(acc[mi][0]); o0.y = f_softplus(acc[mi][1]);
        o0.z = f_softplus(acc[mi][2]); o0.w = f_softplus(acc[mi][3]);
        o1.x = f_softplus(acc[mi][4]); o1.y = f_softplus(acc[mi][5]);
        o1.z = f_softplus(acc[mi][6]); o1.w = f_softplus(acc[mi][7]);
        *(float4*)&dtout[(size_t)m * DINNER + n]     = o0;
        *(float4*)&dtout[(size_t)m * DINNER + n + 4] = o1;
    }
}

// ===================== depthwise convs (position-major, lanes = feature) =====================
__global__ void conv1_k(const float* __restrict__ h1, const float* __restrict__ cw,
                        const float* __restrict__ cb, short* __restrict__ h2b)
{
    int c = blockIdx.x * 256 + threadIdx.x;     // 0..1023
    int m = blockIdx.y;                         // 0..4097
    int b = (m >= LOUT) ? 1 : 0;
    int l = m - b * LOUT;
    float4 wv = ((const float4*)cw)[c];
    const float* w = (const float*)&wv;
    float acc = cb[c];
#pragma unroll
    for (int k = 0; k < 4; k++) {
        int li = l - 2 + k;
        if (li >= 0 && li < LIN)
            acc += h1[((size_t)b * LIN + li) * DMODEL + c] * w[k];
    }
    h2b[(size_t)m * DMODEL + c] = f2b(f_silu(acc));
}

__global__ void conv2_k(const float* __restrict__ xz, const float* __restrict__ cw,
                        const float* __restrict__ cb, float* __restrict__ u,
                        short* __restrict__ ub)
{
    int d = blockIdx.x * 256 + threadIdx.x;     // 0..2047
    int m = blockIdx.y;
    int b = (m >= LOUT) ? 1 : 0;
    int l = m - b * LOUT;
    float4 wv = ((const float4*)cw)[d];
    const float* w = (const float*)&wv;
    float acc = cb[d];
#pragma unroll
    for (int k = 0; k < 4; k++) {
        int li = l - 3 + k;                     // causal pad(3,0)
        if (li >= 0)
            acc += xz[((size_t)b * LOUT + li) * (2 * DINNER) + d] * w[k];
    }
    float s = f_silu(acc);
    u [(size_t)m * DINNER + d] = s;
    ub[(size_t)m * DINNER + d] = f2b(s);
}

// ===================== chunked selective scan (position-major) =====================
__global__ void scan1_k(const float* __restrict__ dt, const float* __restrict__ u,
                        const float* __restrict__ xdbl, const float* __restrict__ A_log,
                        float* __restrict__ sP, float* __restrict__ sH)
{
    int d = blockIdx.x * 256 + threadIdx.x;
    int c = blockIdx.y;
    int b = blockIdx.z;
    int t0 = c * TC;
    int tlen = LOUT - t0; if (tlen > TC) tlen = TC;

    float Ad[16], h[16], P[16];
#pragma unroll
    for (int q = 0; q < 4; q++) {
        float4 av = ((const float4*)A_log)[d * 4 + q];
        Ad[q*4+0] = -__expf(av.x); Ad[q*4+1] = -__expf(av.y);
        Ad[q*4+2] = -__expf(av.z); Ad[q*4+3] = -__expf(av.w);
    }
#pragma unroll
    for (int s = 0; s < 16; s++) { h[s] = 0.f; P[s] = 1.f; }

    size_t row0 = (size_t)b * LOUT + t0;
    const float* dtp = dt + row0 * DINNER + d;
    const float* up  = u  + row0 * DINNER + d;
    const float* Bp  = xdbl + row0 * NPROJ + DTRANK;
    for (int t = 0; t < tlen; t++) {
        float dtt = dtp[(size_t)t * DINNER];
        float du  = dtt * up[(size_t)t * DINNER];
        const float* Bt = Bp + (size_t)t * NPROJ;
#pragma unroll
        for (int s = 0; s < 16; s++) {
            float a = __expf(dtt * Ad[s]);
            h[s] = a * h[s] + du * Bt[s];
            P[s] *= a;
        }
    }
    size_t base = ((size_t)(b * NCH + c) * 16) * DINNER + d;
#pragma unroll
    for (int s = 0; s < 16; s++) {
        sP[base + (size_t)s * DINNER] = P[s];
        sH[base + (size_t)s * DINNER] = h[s];
    }
}

__global__ void scan2_k(const float* __restrict__ sP, float* __restrict__ sH)
{
    int gid = blockIdx.x * 256 + threadIdx.x;   // B*16*DINNER = 65536
    int d = gid & (DINNER - 1);
    int s = (gid >> 11) & 15;
    int b = gid >> 15;
    size_t base = ((size_t)(b * NCH) * 16 + s) * DINNER + d;
    const size_t cstep = (size_t)16 * DINNER;
    float hrun = 0.f;
    for (int c = 0; c < NCH; c++) {
        size_t idx = base + (size_t)c * cstep;
        float Pv = sP[idx], hl = sH[idx];
        sH[idx] = hrun;
        hrun = Pv * hrun + hl;
    }
}

__global__ void scan3_k(const float* __restrict__ dt, const float* __restrict__ u,
                        const float* __restrict__ xdbl, const float* __restrict__ A_log,
                        const float* __restrict__ Dp, const float* __restrict__ xz,
                        const float* __restrict__ sH, short* __restrict__ ymb)
{
    int d = blockIdx.x * 256 + threadIdx.x;
    int c = blockIdx.y;
    int b = blockIdx.z;
    int t0 = c * TC;
    int tlen = LOUT - t0; if (tlen > TC) tlen = TC;

    float Ad[16], h[16];
#pragma unroll
    for (int q = 0; q < 4; q++) {
        float4 av = ((const float4*)A_log)[d * 4 + q];
        Ad[q*4+0] = -__expf(av.x); Ad[q*4+1] = -__expf(av.y);
        Ad[q*4+2] = -__expf(av.z); Ad[q*4+3] = -__expf(av.w);
    }
    size_t sbase = ((size_t)(b * NCH + c) * 16) * DINNER + d;
#pragma unroll
    for (int s = 0; s < 16; s++) h[s] = sH[sbase + (size_t)s * DINNER];

    float Dpd = Dp[d];
    size_t row0 = (size_t)b * LOUT + t0;
    const float* dtp = dt + row0 * DINNER + d;
    const float* up  = u  + row0 * DINNER + d;
    const float* Bp  = xdbl + row0 * NPROJ + DTRANK;
    const float* Cp  = Bp + 16;
    const float* zp  = xz + row0 * (2 * DINNER) + DINNER + d;
    short* yp = ymb + row0 * DINNER + d;
    for (int t = 0; t < tlen; t++) {
        float dtt = dtp[(size_t)t * DINNER];
        float ut  = up[(size_t)t * DINNER];
        float du  = dtt * ut;
        const float* Bt = Bp + (size_t)t * NPROJ;
        const float* Ct = Cp + (size_t)t * NPROJ;
        float y = 0.f;
#pragma unroll
        for (int s = 0; s < 16; s++) {
            float a = __expf(dtt * Ad[s]);
            h[s] = a * h[s] + du * Bt[s];
            y += h[s] * Ct[s];
        }
        float z = zp[(size_t)t * (2 * DINNER)];
        yp[(size_t)t * DINNER] = f2b((y + ut * Dpd) * f_silu(z));
    }
}

// ===================== launcher =====================
extern "C" void kernel_launch(void* const* d_in, const int* in_sizes, int n_in,
                              void* d_out, int out_size, void* d_ws, size_t ws_size,
                              hipStream_t stream)
{
    (void)in_sizes; (void)n_in; (void)out_size; (void)ws_size;
    const float* x        = (const float*)d_in[0];
    const float* ln_g     = (const float*)d_in[1];
    const float* ln_b     = (const float*)d_in[2];
    const float* W_in     = (const float*)d_in[3];
    const float* b_in     = (const float*)d_in[4];
    const float* conv_w   = (const float*)d_in[5];
    const float* conv_b   = (const float*)d_in[6];
    const float* W_inproj = (const float*)d_in[7];
    const float* m_conv_w = (const float*)d_in[8];
    const float* m_conv_b = (const float*)d_in[9];
    const float* W_xproj  = (const float*)d_in[10];
    const float* W_dt     = (const float*)d_in[11];
    const float* b_dt     = (const float*)d_in[12];
    const float* A_log    = (const float*)d_in[13];
    const float* Dp       = (const float*)d_in[14];
    const float* W_outproj= (const float*)d_in[15];
    const float* W_out    = (const float*)d_in[16];
    const float* b_out    = (const float*)d_in[17];
    float* out = (float*)d_out;

    // ---- fp32 region ----
    float* F    = (float*)d_ws;
    float* mu   = F;                                    //      4096
    float* rs   = F + 4096;                             //      4096
    float* h1   = F + 8192;                             // 4096*1024
    float* xz   = h1 + (size_t)MTOT0 * DMODEL;          // 4098*4096
    float* uu   = xz + (size_t)MTOT1 * 2 * DINNER;      // 4098*2048
    float* xdbl = uu + (size_t)MTOT1 * DINNER;          // 4098*96
    float* dt   = xdbl + (size_t)MTOT1 * NPROJ;         // 4098*2048
    float* sP   = dt + (size_t)MTOT1 * DINNER;          // 2*33*16*2048
    float* sH   = sP + (size_t)BATCH * NCH * 16 * DINNER;
    float* fend = sH + (size_t)BATCH * NCH * 16 * DINNER;

    // ---- bf16 region ----
    short* S     = (short*)fend;
    short* h0T   = S;                                   // 4096*1024
    short* h2b   = h0T + (size_t)MTOT0 * DMODEL;        // 4098*1024
    short* ub    = h2b + (size_t)MTOT1 * DMODEL;        // 4098*2048
    short* Wib   = ub  + (size_t)MTOT1 * DINNER;        // 1024*1024
    short* Winpb = Wib   + (size_t)DMODEL * DMODEL;     // 4096*1024
    short* Wxpb  = Winpb + (size_t)(2*DINNER) * DMODEL; // 96*2048
    short* Wdtb  = Wxpb  + (size_t)NPROJ * DINNER;      // 2048*64
    short* Wopb  = Wdtb  + (size_t)DINNER * DTRANK;     // 1024*2048
    short* Wob   = Wopb  + (size_t)DMODEL * DINNER;     // 1024*1024
    // aliases (lifetime-disjoint):
    short* ymb   = ub;             // ymb [4098][2048]; ub dead after xproj-GEMM
    short* o1b   = (short*)h1;     // o1b [4098][1024]; h1 dead after conv1 (16.8MB region)

    // 0) all weight conversions to bf16 (one kernel)
    cvt_all_k<<<8512, 256, 0, stream>>>(W_in, W_inproj, W_xproj, W_dt, W_outproj, W_out,
                                        Wib, Winpb, Wxpb, Wdtb, Wopb, Wob);
    // 1) LN stats + LN-apply/transpose -> h0T bf16 [m][c]
    ln_stats_k<<<dim3(32, 2), 256, 0, stream>>>(x, mu, rs);
    lnT_k<<<dim3(64, 32, 2), 256, 0, stream>>>(x, mu, rs, ln_g, ln_b, h0T);
    // 2) h1 = h0T @ W_in^T + b_in                  (4096 x 1024) fp32
    gemm_bf<1><<<dim3(32, 8), 256, 0, stream>>>(h0T, DMODEL, Wib, DMODEL,
        h1, DMODEL, nullptr, 0, MTOT0, DMODEL, DMODEL, b_in);
    // 3) h2b = bf16(silu(dwconv(h1, pad(2,2))))    (4098 x 1024)
    conv1_k<<<dim3(4, MTOT1), 256, 0, stream>>>(h1, conv_w, conv_b, h2b);
    // 4) xz = h2b @ W_inproj^T                     (4098 x 4096) fp32
    gemm_bf<0><<<dim3(33, 32), 256, 0, stream>>>(h2b, DMODEL, Winpb, DMODEL,
        xz, 2 * DINNER, nullptr, 0, MTOT1, 2 * DINNER, DMODEL, nullptr);
    // 5) u/ub = silu(causal dwconv(xi))            (4098 x 2048)
    conv2_k<<<dim3(8, MTOT1), 256, 0, stream>>>(xz, m_conv_w, m_conv_b, uu, ub);
    // 6) xdbl = ub @ W_xproj^T                     (4098 x 96) fp32
    gemm_bf<0><<<dim3(33, 1), 256, 0, stream>>>(ub, DINNER, Wxpb, DINNER,
        xdbl, NPROJ, nullptr, 0, MTOT1, NPROJ, DINNER, nullptr);
    // 7) dt = softplus(xdbl[:, :64] @ W_dt^T + b_dt)  (4098 x 2048) fused vector kernel
    dtfuse_k<<<1025, 256, 0, stream>>>(xdbl, Wdtb, b_dt, dt);
    // 8-10) chunked scan -> ymb = bf16((y + u*Dp)*silu(z))
    scan1_k<<<dim3(8, NCH, 2), 256, 0, stream>>>(dt, uu, xdbl, A_log, sP, sH);
    scan2_k<<<dim3(256), 256, 0, stream>>>(sP, sH);
    scan3_k<<<dim3(8, NCH, 2), 256, 0, stream>>>(dt, uu, xdbl, A_log, Dp, xz, sH, ymb);
    // 11) o1b = bf16(ymb @ W_outproj^T)            (4098 x 1024)
    gemm_bf<4><<<dim3(33, 8), 256, 0, stream>>>(ymb, DINNER, Wopb, DINNER,
        nullptr, 0, o1b, DMODEL, MTOT1, DMODEL, DINNER, nullptr);
    // 12) out = o1b @ W_out^T + b_out, operand-swapped scatter to (B, DMODEL, LOUT)
    gemm_bf<5><<<dim3(8, 33), 256, 0, stream>>>(Wob, DMODEL, o1b, DMODEL,
        out, 0, nullptr, 0, DMODEL, MTOT1, DMODEL, b_out);
}

// Round 9
// 564.502 us; speedup vs baseline: 4.3383x; 1.0689x over previous
//
#include <hip/hip_runtime.h>
#include <hip/hip_bf16.h>

#define DMODEL 1024
#define DINNER 2048
#define DTRANK 64
#define NPROJ  96
#define BATCH  2
#define LIN    2048
#define LOUT   2049
#define MTOT0  4096   // BATCH*LIN
#define MTOT1  4098   // BATCH*LOUT
#define TC     64
#define NCH    33     // ceil(2049/64)

typedef __attribute__((ext_vector_type(8))) short short8;
typedef __attribute__((ext_vector_type(4))) float f32x4;

__device__ __forceinline__ float f_silu(float x)     { return x / (1.f + __expf(-x)); }
__device__ __forceinline__ float f_softplus(float x) { return (x > 20.f) ? x : log1pf(__expf(x)); }
__device__ __forceinline__ short f2b(float x)
{
    __hip_bfloat16 b = __float2bfloat16(x);
    return *reinterpret_cast<short*>(&b);
}
__device__ __forceinline__ float b2f(short s)
{
    return __uint_as_float(((unsigned)(unsigned short)s) << 16);
}
// async global->LDS, 16B per lane; dst = wave-uniform base + lane*16
__device__ __forceinline__ void gload16(const void* g, void* l)
{
    __builtin_amdgcn_global_load_lds(
        (const __attribute__((address_space(1))) void*)g,
        (__attribute__((address_space(3))) void*)l,
        16, 0, 0);
}

// ===================== LayerNorm stats (mu, rstd per (b,l)) =====================
__global__ void ln_stats_k(const float* __restrict__ x, float* __restrict__ mu, float* __restrict__ rs)
{
    int b  = blockIdx.y;
    int l0 = blockIdx.x * 64;
    int lc = threadIdx.x & 63;
    int q  = threadIdx.x >> 6;          // 0..3
    const float* xb = x + (size_t)b * DMODEL * LIN + (l0 + lc);
    float s = 0.f, ss = 0.f;
    for (int c = q * 256; c < q * 256 + 256; ++c) {
        float v = xb[(size_t)c * LIN];
        s += v; ss += v * v;
    }
    __shared__ float Ss[4][64];
    __shared__ float Sq[4][64];
    Ss[q][lc] = s; Sq[q][lc] = ss;
    __syncthreads();
    if (threadIdx.x < 64) {
        float st = Ss[0][lc] + Ss[1][lc] + Ss[2][lc] + Ss[3][lc];
        float sq = Sq[0][lc] + Sq[1][lc] + Sq[2][lc] + Sq[3][lc];
        float m = st * (1.f / DMODEL);
        float v = sq * (1.f / DMODEL) - m * m;
        mu[b * LIN + l0 + lc] = m;
        rs[b * LIN + l0 + lc] = 1.f / sqrtf(v + 1e-5f);
    }
}

// ============ LN apply + transpose: x (B,DMODEL,LIN) -> h0T bf16 [m][c] ============
__global__ void lnT_k(const float* __restrict__ x, const float* __restrict__ mu,
                      const float* __restrict__ rs, const float* __restrict__ g,
                      const float* __restrict__ be, short* __restrict__ h0T)
{
    __shared__ float T[32][33];
    int l0 = blockIdx.x * 32;
    int c0 = blockIdx.y * 32;
    int b  = blockIdx.z;
    int tx = threadIdx.x & 31, ty = threadIdx.x >> 5;  // ty 0..7
    const float* xb = x + ((size_t)b * DMODEL + c0) * LIN + l0;
#pragma unroll
    for (int i = 0; i < 4; i++) {
        int cl = ty + 8 * i;
        T[cl][tx] = xb[(size_t)cl * LIN + tx];
    }
    __syncthreads();
    int c = c0 + tx;
    float gg = g[c], bb = be[c];
#pragma unroll
    for (int i = 0; i < 4; i++) {
        int ll = ty + 8 * i;
        int m = b * LIN + l0 + ll;
        float v = (T[tx][ll] - mu[m]) * rs[m] * gg + bb;
        h0T[(size_t)m * DMODEL + c] = f2b(v);
    }
}

// ============ W_dt transpose: [2048][64] fp32 -> WdtT [64][2048] fp32 ============
__global__ void wdtT_k(const float* __restrict__ W_dt, float* __restrict__ WdtT)
{
    __shared__ float T[32][33];
    int n0 = blockIdx.x * 32;   // 64 blocks
    int k0 = blockIdx.y * 32;   // 2 blocks
    int tx = threadIdx.x & 31, ty = threadIdx.x >> 5;  // ty 0..7
#pragma unroll
    for (int i = 0; i < 4; i++) {
        int r = ty + 8 * i;
        T[r][tx] = W_dt[(size_t)(n0 + r) * 64 + k0 + tx];
    }
    __syncthreads();
#pragma unroll
    for (int i = 0; i < 4; i++) {
        int r = ty + 8 * i;
        WdtT[(size_t)(k0 + r) * 2048 + n0 + tx] = T[tx][r];
    }
}

// ===================== single fused fp32 -> bf16 weight conversion =====================
// block ranges (each block = 1024 elements): W_in 1024 | W_inproj 4096 | W_xproj 192 |
// W_dt 128 | W_outproj 2048 | W_out 1024   (total 8512)
__global__ void cvt_all_k(const float* __restrict__ W_in, const float* __restrict__ W_inproj,
                          const float* __restrict__ W_xproj, const float* __restrict__ W_dt,
                          const float* __restrict__ W_outproj, const float* __restrict__ W_out,
                          short* __restrict__ Wib, short* __restrict__ Winpb,
                          short* __restrict__ Wxpb, short* __restrict__ Wdtb,
                          short* __restrict__ Wopb, short* __restrict__ Wob)
{
    int b = blockIdx.x;
    const float* s; short* d; int i;
    if      (b < 1024) { s = W_in;      d = Wib;   i = b; }
    else if (b < 5120) { s = W_inproj;  d = Winpb; i = b - 1024; }
    else if (b < 5312) { s = W_xproj;   d = Wxpb;  i = b - 5120; }
    else if (b < 5440) { s = W_dt;      d = Wdtb;  i = b - 5312; }
    else if (b < 7488) { s = W_outproj; d = Wopb;  i = b - 5440; }
    else               { s = W_out;     d = Wob;   i = b - 7488; }
    int idx = (i * 256 + threadIdx.x) * 4;
    float4 v = *(const float4*)(s + idx);
    d[idx + 0] = f2b(v.x); d[idx + 1] = f2b(v.y);
    d[idx + 2] = f2b(v.z); d[idx + 3] = f2b(v.w);
}

// ===================== bf16 MFMA GEMM: C[m][n] = sum_k A[m][k] * W[n][k] =====================
// global_load_lds staging (width 16), linear LDS [128][32] bf16, no padding.
// EPI: 0 plain fp32 C | 1 +bias fp32 | 4 bf16-only into Cb | 5 swapped-scatter (+bias[m])
template<int EPI>
__global__ __launch_bounds__(256) void gemm_bf(
    const short* __restrict__ A, int lda,
    const short* __restrict__ W, int ldb,
    float* __restrict__ C, int ldc,
    short* __restrict__ Cb, int ldcb,
    int M, int N, int K,
    const float* __restrict__ bias)
{
    __shared__ short As[128 * 32];
    __shared__ short Bs[128 * 32];
    int tid  = threadIdx.x;
    int lane = tid & 63, wid = tid >> 6;
    int wr = wid >> 1, wc = wid & 1;          // wave quadrant (2x2 of 64x64)
    int fr = lane & 15, kg = lane >> 4;       // fragment row + k-group
    int m0 = blockIdx.x * 128, n0 = blockIdx.y * 128;

    // staging map: round r in {0,1}: row = (wid*2+r)*16 + lane/4, col = (lane&3)*8 elems
    int scol  = (lane & 3) * 8;
    int srow0 = wid * 32 + (lane >> 2);
    int srow1 = srow0 + 16;
    const short* a0 = A + (size_t)(m0 + srow0) * lda + scol;
    const short* a1 = A + (size_t)(m0 + srow1) * lda + scol;
    const short* b0 = W + (size_t)(n0 + srow0) * ldb + scol;
    const short* b1 = W + (size_t)(n0 + srow1) * ldb + scol;
    char* asd0 = (char*)As + (wid * 2 + 0) * 1024;
    char* asd1 = (char*)As + (wid * 2 + 1) * 1024;
    char* bsd0 = (char*)Bs + (wid * 2 + 0) * 1024;
    char* bsd1 = (char*)Bs + (wid * 2 + 1) * 1024;

    f32x4 acc[4][4];
#pragma unroll
    for (int mi = 0; mi < 4; mi++)
#pragma unroll
        for (int ni = 0; ni < 4; ni++) acc[mi][ni] = (f32x4){0.f, 0.f, 0.f, 0.f};

    for (int k0 = 0; k0 < K; k0 += 32) {
        gload16(a0 + k0, asd0);
        gload16(a1 + k0, asd1);
        gload16(b0 + k0, bsd0);
        gload16(b1 + k0, bsd1);
        __syncthreads();

        short8 af[4], bf[4];
#pragma unroll
        for (int mi = 0; mi < 4; mi++)
            af[mi] = *(const short8*)&As[(wr * 64 + mi * 16 + fr) * 32 + kg * 8];
#pragma unroll
        for (int ni = 0; ni < 4; ni++)
            bf[ni] = *(const short8*)&Bs[(wc * 64 + ni * 16 + fr) * 32 + kg * 8];
#pragma unroll
        for (int mi = 0; mi < 4; mi++)
#pragma unroll
            for (int ni = 0; ni < 4; ni++)
                acc[mi][ni] = __builtin_amdgcn_mfma_f32_16x16x32_bf16(
                    af[mi], bf[ni], acc[mi][ni], 0, 0, 0);
        __syncthreads();
    }

    // epilogue: D element (m_local, n_local): n_local = lane&15, m_local = (lane>>4)*4 + reg
#pragma unroll
    for (int ni = 0; ni < 4; ni++) {
        int n = n0 + wc * 64 + ni * 16 + fr;
        if (n >= N) continue;
        float bv = 0.f;
        if (EPI == 1) bv = bias[n];
#pragma unroll
        for (int mi = 0; mi < 4; mi++) {
#pragma unroll
            for (int r = 0; r < 4; r++) {
                int m = m0 + wr * 64 + mi * 16 + kg * 4 + r;
                if (m >= M) continue;
                float v = acc[mi][ni][r];
                if (EPI == 1) v += bv;
                if (EPI == 5) {
                    float vb = v + bias[m];
                    int bq = (n >= LOUT) ? 1 : 0;
                    int l  = n - bq * LOUT;
                    C[((size_t)bq * DMODEL + m) * LOUT + l] = vb;
                } else if (EPI == 4) {
                    Cb[(size_t)m * ldcb + n] = f2b(v);
                } else {
                    C[(size_t)m * ldc + n] = v;
                }
            }
        }
    }
}

// ============ fused dt kernel v2: dt[m][n] = softplus(xdbl[m][0:64] . WdtT[:, n] + b_dt[n]) ============
// WdtT fp32 [64][2048] (k-major). Block: 8 m-rows x 2048 n. Thread: 8 m x (4+4) n.
// Weight reads: lane-consecutive float4 (fully coalesced, L2-resident 512 KB).
__global__ __launch_bounds__(256) void dtfuse2_k(const float* __restrict__ xdbl,
                                                 const float* __restrict__ WdtT,
                                                 const float* __restrict__ b_dt,
                                                 float* __restrict__ dtout)
{
    int t  = threadIdx.x;
    int m0 = blockIdx.x * 8;
    __shared__ float dr[8][64];
    {
        int k = t & 63, r = t >> 6;             // r 0..3
        int ma = m0 + r, mb = m0 + r + 4;
        dr[r][k]     = (ma < MTOT1) ? xdbl[(size_t)ma * NPROJ + k] : 0.f;
        dr[r + 4][k] = (mb < MTOT1) ? xdbl[(size_t)mb * NPROJ + k] : 0.f;
    }
    __syncthreads();

    int n0 = t * 4;                             // cols [n0,n0+3] and [n0+1024, n0+1027]
    f32x4 acc0[8], acc1[8];
#pragma unroll
    for (int mi = 0; mi < 8; mi++) {
        acc0[mi] = (f32x4){0.f, 0.f, 0.f, 0.f};
        acc1[mi] = (f32x4){0.f, 0.f, 0.f, 0.f};
    }

    for (int k = 0; k < 64; k += 4) {
        f32x4 w0[4], w1[4];
#pragma unroll
        for (int e = 0; e < 4; e++) {
            w0[e] = *(const f32x4*)&WdtT[(size_t)(k + e) * 2048 + n0];
            w1[e] = *(const f32x4*)&WdtT[(size_t)(k + e) * 2048 + n0 + 1024];
        }
#pragma unroll
        for (int mi = 0; mi < 8; mi++) {
            f32x4 d = *(const f32x4*)&dr[mi][k];
#pragma unroll
            for (int e = 0; e < 4; e++) {
                acc0[mi] += d[e] * w0[e];
                acc1[mi] += d[e] * w1[e];
            }
        }
    }

    f32x4 b0 = *(const f32x4*)&b_dt[n0];
    f32x4 b1 = *(const f32x4*)&b_dt[n0 + 1024];
#pragma unroll
    for (int mi = 0; mi < 8; mi++) {
        int m = m0 + mi;
        if (m >= MTOT1) continue;
        f32x4 v0, v1;
#pragma unroll
        for (int e = 0; e < 4; e++) {
            v0[e] = f_softplus(acc0[mi][e] + b0[e]);
            v1[e] = f_softplus(acc1[mi][e] + b1[e]);
        }
        *(f32x4*)&dtout[(size_t)m * DINNER + n0]        = v0;
        *(f32x4*)&dtout[(size_t)m * DINNER + n0 + 1024] = v1;
    }
}

// ===================== depthwise convs (position-major, lanes = feature) =====================
__global__ void conv1_k(const float* __restrict__ h1, const float* __restrict__ cw,
                        const float* __restrict__ cb, short* __restrict__ h2b)
{
    int c = blockIdx.x * 256 + threadIdx.x;     // 0..1023
    int m = blockIdx.y;                         // 0..4097
    int b = (m >= LOUT) ? 1 : 0;
    int l = m - b * LOUT;
    float4 wv = ((const float4*)cw)[c];
    const float* w = (const float*)&wv;
    float acc = cb[c];
#pragma unroll
    for (int k = 0; k < 4; k++) {
        int li = l - 2 + k;
        if (li >= 0 && li < LIN)
            acc += h1[((size_t)b * LIN + li) * DMODEL + c] * w[k];
    }
    h2b[(size_t)m * DMODEL + c] = f2b(f_silu(acc));
}

__global__ void conv2_k(const float* __restrict__ xz, const float* __restrict__ cw,
                        const float* __restrict__ cb, float* __restrict__ u,
                        short* __restrict__ ub)
{
    int d = blockIdx.x * 256 + threadIdx.x;     // 0..2047
    int m = blockIdx.y;
    int b = (m >= LOUT) ? 1 : 0;
    int l = m - b * LOUT;
    float4 wv = ((const float4*)cw)[d];
    const float* w = (const float*)&wv;
    float acc = cb[d];
#pragma unroll
    for (int k = 0; k < 4; k++) {
        int li = l - 3 + k;                     // causal pad(3,0)
        if (li >= 0)
            acc += xz[((size_t)b * LOUT + li) * (2 * DINNER) + d] * w[k];
    }
    float s = f_silu(acc);
    u [(size_t)m * DINNER + d] = s;
    ub[(size_t)m * DINNER + d] = f2b(s);
}

// ===================== chunked selective scan (position-major) =====================
__global__ void scan1_k(const float* __restrict__ dt, const float* __restrict__ u,
                        const float* __restrict__ xdbl, const float* __restrict__ A_log,
                        float* __restrict__ sP, float* __restrict__ sH)
{
    int d = blockIdx.x * 256 + threadIdx.x;
    int c = blockIdx.y;
    int b = blockIdx.z;
    int t0 = c * TC;
    int tlen = LOUT - t0; if (tlen > TC) tlen = TC;

    float Ad[16], h[16], P[16];
#pragma unroll
    for (int q = 0; q < 4; q++) {
        float4 av = ((const float4*)A_log)[d * 4 + q];
        Ad[q*4+0] = -__expf(av.x); Ad[q*4+1] = -__expf(av.y);
        Ad[q*4+2] = -__expf(av.z); Ad[q*4+3] = -__expf(av.w);
    }
#pragma unroll
    for (int s = 0; s < 16; s++) { h[s] = 0.f; P[s] = 1.f; }

    size_t row0 = (size_t)b * LOUT + t0;
    const float* dtp = dt + row0 * DINNER + d;
    const float* up  = u  + row0 * DINNER + d;
    const float* Bp  = xdbl + row0 * NPROJ + DTRANK;
    for (int t = 0; t < tlen; t++) {
        float dtt = dtp[(size_t)t * DINNER];
        float du  = dtt * up[(size_t)t * DINNER];
        const float* Bt = Bp + (size_t)t * NPROJ;
#pragma unroll
        for (int s = 0; s < 16; s++) {
            float a = __expf(dtt * Ad[s]);
            h[s] = a * h[s] + du * Bt[s];
            P[s] *= a;
        }
    }
    size_t base = ((size_t)(b * NCH + c) * 16) * DINNER + d;
#pragma unroll
    for (int s = 0; s < 16; s++) {
        sP[base + (size_t)s * DINNER] = P[s];
        sH[base + (size_t)s * DINNER] = h[s];
    }
}

__global__ void scan2_k(const float* __restrict__ sP, float* __restrict__ sH)
{
    int gid = blockIdx.x * 256 + threadIdx.x;   // B*16*DINNER = 65536
    int d = gid & (DINNER - 1);
    int s = (gid >> 11) & 15;
    int b = gid >> 15;
    size_t base = ((size_t)(b * NCH) * 16 + s) * DINNER + d;
    const size_t cstep = (size_t)16 * DINNER;
    float hrun = 0.f;
    for (int c = 0; c < NCH; c++) {
        size_t idx = base + (size_t)c * cstep;
        float Pv = sP[idx], hl = sH[idx];
        sH[idx] = hrun;
        hrun = Pv * hrun + hl;
    }
}

__global__ void scan3_k(const float* __restrict__ dt, const float* __restrict__ u,
                        const float* __restrict__ xdbl, const float* __restrict__ A_log,
                        const float* __restrict__ Dp, const float* __restrict__ xz,
                        const float* __restrict__ sH, short* __restrict__ ymb)
{
    int d = blockIdx.x * 256 + threadIdx.x;
    int c = blockIdx.y;
    int b = blockIdx.z;
    int t0 = c * TC;
    int tlen = LOUT - t0; if (tlen > TC) tlen = TC;

    float Ad[16], h[16];
#pragma unroll
    for (int q = 0; q < 4; q++) {
        float4 av = ((const float4*)A_log)[d * 4 + q];
        Ad[q*4+0] = -__expf(av.x); Ad[q*4+1] = -__expf(av.y);
        Ad[q*4+2] = -__expf(av.z); Ad[q*4+3] = -__expf(av.w);
    }
    size_t sbase = ((size_t)(b * NCH + c) * 16) * DINNER + d;
#pragma unroll
    for (int s = 0; s < 16; s++) h[s] = sH[sbase + (size_t)s * DINNER];

    float Dpd = Dp[d];
    size_t row0 = (size_t)b * LOUT + t0;
    const float* dtp = dt + row0 * DINNER + d;
    const float* up  = u  + row0 * DINNER + d;
    const float* Bp  = xdbl + row0 * NPROJ + DTRANK;
    const float* Cp  = Bp + 16;
    const float* zp  = xz + row0 * (2 * DINNER) + DINNER + d;
    short* yp = ymb + row0 * DINNER + d;
    for (int t = 0; t < tlen; t++) {
        float dtt = dtp[(size_t)t * DINNER];
        float ut  = up[(size_t)t * DINNER];
        float du  = dtt * ut;
        const float* Bt = Bp + (size_t)t * NPROJ;
        const float* Ct = Cp + (size_t)t * NPROJ;
        float y = 0.f;
#pragma unroll
        for (int s = 0; s < 16; s++) {
            float a = __expf(dtt * Ad[s]);
            h[s] = a * h[s] + du * Bt[s];
            y += h[s] * Ct[s];
        }
        float z = zp[(size_t)t * (2 * DINNER)];
        yp[(size_t)t * DINNER] = f2b((y + ut * Dpd) * f_silu(z));
    }
}

// ===================== launcher =====================
extern "C" void kernel_launch(void* const* d_in, const int* in_sizes, int n_in,
                              void* d_out, int out_size, void* d_ws, size_t ws_size,
                              hipStream_t stream)
{
    (void)in_sizes; (void)n_in; (void)out_size; (void)ws_size;
    const float* x        = (const float*)d_in[0];
    const float* ln_g     = (const float*)d_in[1];
    const float* ln_b     = (const float*)d_in[2];
    const float* W_in     = (const float*)d_in[3];
    const float* b_in     = (const float*)d_in[4];
    const float* conv_w   = (const float*)d_in[5];
    const float* conv_b   = (const float*)d_in[6];
    const float* W_inproj = (const float*)d_in[7];
    const float* m_conv_w = (const float*)d_in[8];
    const float* m_conv_b = (const float*)d_in[9];
    const float* W_xproj  = (const float*)d_in[10];
    const float* W_dt     = (const float*)d_in[11];
    const float* b_dt     = (const float*)d_in[12];
    const float* A_log    = (const float*)d_in[13];
    const float* Dp       = (const float*)d_in[14];
    const float* W_outproj= (const float*)d_in[15];
    const float* W_out    = (const float*)d_in[16];
    const float* b_out    = (const float*)d_in[17];
    float* out = (float*)d_out;

    // ---- fp32 region ----
    float* F    = (float*)d_ws;
    float* mu   = F;                                    //      4096
    float* rs   = F + 4096;                             //      4096
    float* h1   = F + 8192;                             // 4096*1024
    float* xz   = h1 + (size_t)MTOT0 * DMODEL;          // 4098*4096
    float* uu   = xz + (size_t)MTOT1 * 2 * DINNER;      // 4098*2048
    float* xdbl = uu + (size_t)MTOT1 * DINNER;          // 4098*96
    float* dt   = xdbl + (size_t)MTOT1 * NPROJ;         // 4098*2048
    float* sP   = dt + (size_t)MTOT1 * DINNER;          // 2*33*16*2048
    float* sH   = sP + (size_t)BATCH * NCH * 16 * DINNER;
    float* WdtT = sH + (size_t)BATCH * NCH * 16 * DINNER;  // 64*2048 fp32
    float* fend = WdtT + (size_t)DTRANK * DINNER;

    // ---- bf16 region ----
    short* S     = (short*)fend;
    short* h0T   = S;                                   // 4096*1024
    short* h2b   = h0T + (size_t)MTOT0 * DMODEL;        // 4098*1024
    short* ub    = h2b + (size_t)MTOT1 * DMODEL;        // 4098*2048
    short* Wib   = ub  + (size_t)MTOT1 * DINNER;        // 1024*1024
    short* Winpb = Wib   + (size_t)DMODEL * DMODEL;     // 4096*1024
    short* Wxpb  = Winpb + (size_t)(2*DINNER) * DMODEL; // 96*2048
    short* Wdtb  = Wxpb  + (size_t)NPROJ * DINNER;      // 2048*64 (unused by dtfuse2; kept for cvt layout)
    short* Wopb  = Wdtb  + (size_t)DINNER * DTRANK;     // 1024*2048
    short* Wob   = Wopb  + (size_t)DMODEL * DINNER;     // 1024*1024
    // aliases (lifetime-disjoint):
    short* ymb   = ub;             // ymb [4098][2048]; ub dead after xproj-GEMM
    short* o1b   = (short*)h1;     // o1b [4098][1024]; h1 dead after conv1 (16.8MB region)

    // 0) all weight conversions to bf16 (one kernel) + dt-weight fp32 transpose
    cvt_all_k<<<8512, 256, 0, stream>>>(W_in, W_inproj, W_xproj, W_dt, W_outproj, W_out,
                                        Wib, Winpb, Wxpb, Wdtb, Wopb, Wob);
    wdtT_k<<<dim3(64, 2), 256, 0, stream>>>(W_dt, WdtT);
    // 1) LN stats + LN-apply/transpose -> h0T bf16 [m][c]
    ln_stats_k<<<dim3(32, 2), 256, 0, stream>>>(x, mu, rs);
    lnT_k<<<dim3(64, 32, 2), 256, 0, stream>>>(x, mu, rs, ln_g, ln_b, h0T);
    // 2) h1 = h0T @ W_in^T + b_in                  (4096 x 1024) fp32
    gemm_bf<1><<<dim3(32, 8), 256, 0, stream>>>(h0T, DMODEL, Wib, DMODEL,
        h1, DMODEL, nullptr, 0, MTOT0, DMODEL, DMODEL, b_in);
    // 3) h2b = bf16(silu(dwconv(h1, pad(2,2))))    (4098 x 1024)
    conv1_k<<<dim3(4, MTOT1), 256, 0, stream>>>(h1, conv_w, conv_b, h2b);
    // 4) xz = h2b @ W_inproj^T                     (4098 x 4096) fp32
    gemm_bf<0><<<dim3(33, 32), 256, 0, stream>>>(h2b, DMODEL, Winpb, DMODEL,
        xz, 2 * DINNER, nullptr, 0, MTOT1, 2 * DINNER, DMODEL, nullptr);
    // 5) u/ub = silu(causal dwconv(xi))            (4098 x 2048)
    conv2_k<<<dim3(8, MTOT1), 256, 0, stream>>>(xz, m_conv_w, m_conv_b, uu, ub);
    // 6) xdbl = ub @ W_xproj^T                     (4098 x 96) fp32
    gemm_bf<0><<<dim3(33, 1), 256, 0, stream>>>(ub, DINNER, Wxpb, DINNER,
        xdbl, NPROJ, nullptr, 0, MTOT1, NPROJ, DINNER, nullptr);
    // 7) dt = softplus(xdbl[:, :64] @ W_dt^T + b_dt)  (4098 x 2048) coalesced fused kernel
    dtfuse2_k<<<513, 256, 0, stream>>>(xdbl, WdtT, b_dt, dt);
    // 8-10) chunked scan -> ymb = bf16((y + u*Dp)*silu(z))
    scan1_k<<<dim3(8, NCH, 2), 256, 0, stream>>>(dt, uu, xdbl, A_log, sP, sH);
    scan2_k<<<dim3(256), 256, 0, stream>>>(sP, sH);
    scan3_k<<<dim3(8, NCH, 2), 256, 0, stream>>>(dt, uu, xdbl, A_log, Dp, xz, sH, ymb);
    // 11) o1b = bf16(ymb @ W_outproj^T)            (4098 x 1024)
    gemm_bf<4><<<dim3(33, 8), 256, 0, stream>>>(ymb, DINNER, Wopb, DINNER,
        nullptr, 0, o1b, DMODEL, MTOT1, DMODEL, DINNER, nullptr);
    // 12) out = o1b @ W_out^T + b_out, operand-swapped scatter to (B, DMODEL, LOUT)
    gemm_bf<5><<<dim3(8, 33), 256, 0, stream>>>(Wob, DMODEL, o1b, DMODEL,
        out, 0, nullptr, 0, DMODEL, MTOT1, DMODEL, b_out);
}